// Round 5
// baseline (756.711 us; speedup 1.0000x reference)
//
#include <hip/hip_runtime.h>
#include <cstdint>
#include <math.h>

constexpr int NN = 32768;
constexpr int KK = 4096;
constexpr int DD = 256;

typedef __attribute__((ext_vector_type(8))) short short8;
typedef __attribute__((ext_vector_type(4))) float f32x4;

// ---------- monotone float<->u32 (order-preserving incl. negatives) ----------
__device__ __forceinline__ unsigned mono(float v) {
  unsigned u = __float_as_uint(v);
  return (u & 0x80000000u) ? ~u : (u | 0x80000000u);
}
__device__ __forceinline__ float unmono(unsigned u) {
  u = (u & 0x80000000u) ? (u & 0x7fffffffu) : ~u;
  return __uint_as_float(u);
}

// ============ numpy-replica row sum-of-squares (verified bit-exact r2) ============
__device__ __forceinline__ void sq16(const float4* __restrict__ p, int b, float q[16]) {
#pragma unroll
  for (int j = 0; j < 4; ++j) {
    const float4 v = p[b * 4 + j];
    q[4 * j + 0] = v.x * v.x;
    q[4 * j + 1] = v.y * v.y;
    q[4 * j + 2] = v.z * v.z;
    q[4 * j + 3] = v.w * v.w;
  }
}
__device__ __forceinline__ float np_pw128_sq(const float4* __restrict__ p, int b0) {
  float A[16], B[16], r01[16], r23[16], q0123[16], r45[16], r67[16];
  sq16(p, b0 + 0, A); sq16(p, b0 + 1, B);
#pragma unroll
  for (int l = 0; l < 16; ++l) r01[l] = A[l] + B[l];
  sq16(p, b0 + 2, A); sq16(p, b0 + 3, B);
#pragma unroll
  for (int l = 0; l < 16; ++l) r23[l] = A[l] + B[l];
#pragma unroll
  for (int l = 0; l < 16; ++l) q0123[l] = r01[l] + r23[l];
  sq16(p, b0 + 4, A); sq16(p, b0 + 5, B);
#pragma unroll
  for (int l = 0; l < 16; ++l) r45[l] = A[l] + B[l];
  sq16(p, b0 + 6, A); sq16(p, b0 + 7, B);
#pragma unroll
  for (int l = 0; l < 16; ++l) r67[l] = A[l] + B[l];
  float s[16];
#pragma unroll
  for (int l = 0; l < 16; ++l) s[l] = q0123[l] + (r45[l] + r67[l]);
  float t[8];
#pragma unroll
  for (int l = 0; l < 8; ++l) t[l] = s[l] + s[l + 8];
  float u[4];
#pragma unroll
  for (int l = 0; l < 4; ++l) u[l] = t[l] + t[l + 4];
  return (u[0] + u[2]) + (u[1] + u[3]);
}

__global__ __launch_bounds__(256) void vq_norms(const float* __restrict__ src,
                                                float* __restrict__ dst, int nrows) {
  const int row = blockIdx.x * blockDim.x + threadIdx.x;
  if (row >= nrows) return;
  const float4* p = reinterpret_cast<const float4*>(src + (size_t)row * DD);
  dst[row] = np_pw128_sq(p, 0) + np_pw128_sq(p, 8);
}

__global__ __launch_bounds__(256) void vq_init(unsigned* __restrict__ tmin, int n) {
  const int i = blockIdx.x * blockDim.x + threadIdx.x;
  if (i < n) tmin[i] = 0xFFFFFFFFu;
}

// ============ MFMA approx-distance pass ============
// 3-term bf16 split GEMM: mm^ = xh*ch + xh*cl + xl*ch (fp32 MFMA accum).
// P^ = (fl(xn+cn) - xn) - 2*mm^  (range ±0.03 -> fp32 resolution ~1e-9).
// tmin[row][tile64] = min P^ over the 64 codewords of the tile (monotone u32).
__device__ __forceinline__ unsigned short bf16_rne(float f) {
  unsigned u = __float_as_uint(f);
  return (unsigned short)((u + 0x7fffu + ((u >> 16) & 1u)) >> 16);
}
__device__ __forceinline__ int swz16(int row, int k) {  // u16-element offset in [128][32] tile
  return (row * 32 + k) ^ ((row & 7) << 3);             // 16B-granule XOR swizzle
}

__global__ __launch_bounds__(256) void vq_mfma(const float* __restrict__ x,
                                               const float* __restrict__ cb,
                                               const float* __restrict__ xn,
                                               const float* __restrict__ cn,
                                               unsigned* __restrict__ tmin) {
  __shared__ __align__(16) unsigned short sXH[128 * 32];
  __shared__ __align__(16) unsigned short sXL[128 * 32];
  __shared__ __align__(16) unsigned short sCH[128 * 32];
  __shared__ __align__(16) unsigned short sCL[128 * 32];

  const int tid = threadIdx.x;
  const int lane = tid & 63;
  const int wid = tid >> 6;
  const int wm = wid >> 1, wn = wid & 1;  // wave covers rows wm*64.., cols wn*64..
  const int row0 = blockIdx.x * 128;
  const int kc0 = blockIdx.y * 128;

  const int srow = tid >> 1;       // staging row 0..127
  const int sh = (tid & 1) * 16;   // staging d-offset half

  f32x4 acc[4][4];
#pragma unroll
  for (int m = 0; m < 4; ++m)
#pragma unroll
    for (int n = 0; n < 4; ++n) acc[m][n] = (f32x4)0.f;

  for (int dc = 0; dc < DD; dc += 32) {
    // load 16 fp32 of x-row and 16 of c-row to regs
    const float4* xg = reinterpret_cast<const float4*>(x + (size_t)(row0 + srow) * DD + dc + sh);
    const float4* cg = reinterpret_cast<const float4*>(cb + (size_t)(kc0 + srow) * DD + dc + sh);
    float fx[16], fc[16];
#pragma unroll
    for (int j = 0; j < 4; ++j) {
      const float4 v = xg[j];
      fx[4 * j] = v.x; fx[4 * j + 1] = v.y; fx[4 * j + 2] = v.z; fx[4 * j + 3] = v.w;
    }
#pragma unroll
    for (int j = 0; j < 4; ++j) {
      const float4 v = cg[j];
      fc[4 * j] = v.x; fc[4 * j + 1] = v.y; fc[4 * j + 2] = v.z; fc[4 * j + 3] = v.w;
    }
    // split to (hi,lo) bf16, packed 2-per-u32
    unsigned xhw[8], xlw[8], chw[8], clw[8];
#pragma unroll
    for (int j = 0; j < 8; ++j) {
      unsigned short h0 = bf16_rne(fx[2 * j]), h1 = bf16_rne(fx[2 * j + 1]);
      float hf0 = __uint_as_float((unsigned)h0 << 16), hf1 = __uint_as_float((unsigned)h1 << 16);
      unsigned short l0 = bf16_rne(fx[2 * j] - hf0), l1 = bf16_rne(fx[2 * j + 1] - hf1);
      xhw[j] = (unsigned)h0 | ((unsigned)h1 << 16);
      xlw[j] = (unsigned)l0 | ((unsigned)l1 << 16);
      h0 = bf16_rne(fc[2 * j]); h1 = bf16_rne(fc[2 * j + 1]);
      hf0 = __uint_as_float((unsigned)h0 << 16); hf1 = __uint_as_float((unsigned)h1 << 16);
      l0 = bf16_rne(fc[2 * j] - hf0); l1 = bf16_rne(fc[2 * j + 1] - hf1);
      chw[j] = (unsigned)h0 | ((unsigned)h1 << 16);
      clw[j] = (unsigned)l0 | ((unsigned)l1 << 16);
    }
    __syncthreads();  // prior iteration's fragment reads complete
#pragma unroll
    for (int half = 0; half < 2; ++half) {
      const int off = swz16(srow, sh + half * 8);
      *reinterpret_cast<uint4*>(&sXH[off]) = make_uint4(xhw[4 * half], xhw[4 * half + 1], xhw[4 * half + 2], xhw[4 * half + 3]);
      *reinterpret_cast<uint4*>(&sXL[off]) = make_uint4(xlw[4 * half], xlw[4 * half + 1], xlw[4 * half + 2], xlw[4 * half + 3]);
      *reinterpret_cast<uint4*>(&sCH[off]) = make_uint4(chw[4 * half], chw[4 * half + 1], chw[4 * half + 2], chw[4 * half + 3]);
      *reinterpret_cast<uint4*>(&sCL[off]) = make_uint4(clw[4 * half], clw[4 * half + 1], clw[4 * half + 2], clw[4 * half + 3]);
    }
    __syncthreads();

    // fragment loads + MFMA. A/B frag: elem i of lane = M[base + (lane&15)][8*(lane>>4)+i]
    const int kg = (lane >> 4) * 8;
    short8 fbh[4], fbl[4];
#pragma unroll
    for (int n = 0; n < 4; ++n) {
      const int off = swz16(wn * 64 + n * 16 + (lane & 15), kg);
      fbh[n] = *reinterpret_cast<const short8*>(&sCH[off]);
      fbl[n] = *reinterpret_cast<const short8*>(&sCL[off]);
    }
#pragma unroll
    for (int m = 0; m < 4; ++m) {
      const int off = swz16(wm * 64 + m * 16 + (lane & 15), kg);
      const short8 fah = *reinterpret_cast<const short8*>(&sXH[off]);
      const short8 fal = *reinterpret_cast<const short8*>(&sXL[off]);
#pragma unroll
      for (int n = 0; n < 4; ++n) {
        acc[m][n] = __builtin_amdgcn_mfma_f32_16x16x32_bf16(fah, fbh[n], acc[m][n], 0, 0, 0);
        acc[m][n] = __builtin_amdgcn_mfma_f32_16x16x32_bf16(fah, fbl[n], acc[m][n], 0, 0, 0);
        acc[m][n] = __builtin_amdgcn_mfma_f32_16x16x32_bf16(fal, fbh[n], acc[m][n], 0, 0, 0);
      }
    }
  }

  // epilogue: P^ per element; D layout: col = lane&15, row = 4*(lane>>4)+j (m89-verified)
  const int lr = lane >> 4, lc = lane & 15;
  const int tile = blockIdx.y * 2 + wn;
#pragma unroll
  for (int m = 0; m < 4; ++m) {
    float xnv[4];
#pragma unroll
    for (int j = 0; j < 4; ++j) xnv[j] = xn[row0 + wm * 64 + m * 16 + lr * 4 + j];
    float pm[4] = {INFINITY, INFINITY, INFINITY, INFINITY};
#pragma unroll
    for (int n = 0; n < 4; ++n) {
      const float cnv = cn[kc0 + wn * 64 + n * 16 + lc];
#pragma unroll
      for (int j = 0; j < 4; ++j) {
        const float A = xnv[j] + cnv;                       // fl(xn+cn)
        const float p = fmaf(-2.f, acc[m][n][j], A - xnv[j]);  // (A-xn) exact (Sterbenz)
        pm[j] = fminf(pm[j], p);
      }
    }
#pragma unroll
    for (int off = 1; off < 16; off <<= 1) {
#pragma unroll
      for (int j = 0; j < 4; ++j) pm[j] = fminf(pm[j], __shfl_xor(pm[j], off));
    }
    if (lc == 0) {
#pragma unroll
      for (int j = 0; j < 4; ++j) {
        const int row = row0 + wm * 64 + m * 16 + lr * 4 + j;
        atomicMin(&tmin[(size_t)row * 64 + tile], mono(pm[j]));
      }
    }
  }
}

// ============ exact rescore of qualifying tiles ============
// For each row: gmin = min tmin; tiles with tmin < gmin + W get all 64 k's
// re-scored with the exact ascending-d fp32 FMA chain + exact numpy epilogue.
// Lex-min on (mono(dist) || k) == numpy first-index argmin.
__global__ __launch_bounds__(256) void vq_rescore(const float* __restrict__ x,
                                                  const float* __restrict__ cb,
                                                  const float* __restrict__ xn,
                                                  const float* __restrict__ cn,
                                                  const unsigned* __restrict__ tmin,
                                                  int* __restrict__ inds) {
  const int lane = threadIdx.x & 63;
  const int row = blockIdx.x * 4 + (threadIdx.x >> 6);
  const unsigned tv = tmin[(size_t)row * 64 + lane];
  unsigned mv = tv;
#pragma unroll
  for (int off = 32; off; off >>= 1) mv = min(mv, (unsigned)__shfl_xor((int)mv, off));
  const float xnr = xn[row];
  // W >= ulp(dist) + 2*approx_err + safety:  ulp <= xn*2.4e-7
  const float thresh = unmono(mv) + (xnr * 3e-7f + 4e-6f);
  const unsigned tq = mono(thresh);
  unsigned long long qmask = __ballot(tv <= tq);

  const float* xp = x + (size_t)row * DD;
  unsigned long long best = ~0ull;
  while (qmask) {
    const int s = __ffsll(qmask) - 1;
    qmask &= qmask - 1;
    const int k = s * 64 + lane;
    const float* cp = cb + (size_t)k * DD;
    float dot = 0.f;
#pragma unroll 8
    for (int d = 0; d < DD; ++d) dot = fmaf(xp[d], cp[d], dot);
    const float A = xnr + cn[k];
    const float dist = fmaf(-2.f, dot, A);  // == fl(A - fl(2*dot)) (2*dot exact)
    const unsigned long long cand = ((unsigned long long)mono(dist) << 32) | (unsigned)k;
    best = best < cand ? best : cand;
  }
#pragma unroll
  for (int off = 32; off; off >>= 1) {
    const unsigned long long o = __shfl_xor(best, off);
    best = best < o ? best : o;
  }
  if (lane == 0) inds[row] = (int)(best & 0xffffffffu);
}

// ============ gather + STE output ============
__global__ __launch_bounds__(256) void vq_out(const float* __restrict__ x,
                                              const float* __restrict__ cb,
                                              const int* __restrict__ inds,
                                              float* __restrict__ out) {
  const int w = (blockIdx.x * blockDim.x + threadIdx.x) >> 6;
  const int lane = threadIdx.x & 63;
  if (w >= NN) return;
  const int k = inds[w];
  const float4 xv = *reinterpret_cast<const float4*>(x + (size_t)w * DD + lane * 4);
  const float4 cv = *reinterpret_cast<const float4*>(cb + (size_t)k * DD + lane * 4);
  float4 o;
  o.x = xv.x + (cv.x - xv.x);
  o.y = xv.y + (cv.y - xv.y);
  o.z = xv.z + (cv.z - xv.z);
  o.w = xv.w + (cv.w - xv.w);
  *reinterpret_cast<float4*>(out + (size_t)w * DD + lane * 4) = o;
}

extern "C" void kernel_launch(void* const* d_in, const int* in_sizes, int n_in,
                              void* d_out, int out_size, void* d_ws, size_t ws_size,
                              hipStream_t stream) {
  const float* x = (const float*)d_in[0];
  const float* cb = (const float*)d_in[1];
  float* out = (float*)d_out;

  // ws: xn 128KB @0 | cn 16KB @128K | tmin 8MB @144K | inds 128KB @ 144K+8M
  float* xn = (float*)d_ws;
  float* cn = (float*)((char*)d_ws + 131072);
  unsigned* tmin = (unsigned*)((char*)d_ws + 147456);
  int* inds = (int*)((char*)d_ws + 147456 + (size_t)NN * 64 * 4);

  vq_init<<<(NN * 64) / 256, 256, 0, stream>>>(tmin, NN * 64);
  vq_norms<<<NN / 256, 256, 0, stream>>>(x, xn, NN);
  vq_norms<<<KK / 256, 256, 0, stream>>>(cb, cn, KK);
  dim3 mgrid(NN / 128, KK / 128);
  vq_mfma<<<mgrid, 256, 0, stream>>>(x, cb, xn, cn, tmin);
  vq_rescore<<<NN / 4, 256, 0, stream>>>(x, cb, xn, cn, tmin, inds);
  vq_out<<<NN / 4, 256, 0, stream>>>(x, cb, inds, out);
}

// Round 6
// 755.963 us; speedup vs baseline: 1.0010x; 1.0010x over previous
//
#include <hip/hip_runtime.h>
#include <cstdint>
#include <math.h>

constexpr int NN = 32768;
constexpr int KK = 4096;
constexpr int DD = 256;

typedef __attribute__((ext_vector_type(8))) short short8;
typedef __attribute__((ext_vector_type(4))) float f32x4;

// ---------- monotone float<->u32 (order-preserving incl. negatives) ----------
__device__ __forceinline__ unsigned mono(float v) {
  unsigned u = __float_as_uint(v);
  return (u & 0x80000000u) ? ~u : (u | 0x80000000u);
}
__device__ __forceinline__ float unmono(unsigned u) {
  u = (u & 0x80000000u) ? (u & 0x7fffffffu) : ~u;
  return __uint_as_float(u);
}

// ============ numpy-replica row sum-of-squares (verified bit-exact r2) ============
__device__ __forceinline__ void sq16(const float4* __restrict__ p, int b, float q[16]) {
#pragma unroll
  for (int j = 0; j < 4; ++j) {
    const float4 v = p[b * 4 + j];
    q[4 * j + 0] = v.x * v.x;
    q[4 * j + 1] = v.y * v.y;
    q[4 * j + 2] = v.z * v.z;
    q[4 * j + 3] = v.w * v.w;
  }
}
__device__ __forceinline__ float np_pw128_sq(const float4* __restrict__ p, int b0) {
  float A[16], B[16], r01[16], r23[16], q0123[16], r45[16], r67[16];
  sq16(p, b0 + 0, A); sq16(p, b0 + 1, B);
#pragma unroll
  for (int l = 0; l < 16; ++l) r01[l] = A[l] + B[l];
  sq16(p, b0 + 2, A); sq16(p, b0 + 3, B);
#pragma unroll
  for (int l = 0; l < 16; ++l) r23[l] = A[l] + B[l];
#pragma unroll
  for (int l = 0; l < 16; ++l) q0123[l] = r01[l] + r23[l];
  sq16(p, b0 + 4, A); sq16(p, b0 + 5, B);
#pragma unroll
  for (int l = 0; l < 16; ++l) r45[l] = A[l] + B[l];
  sq16(p, b0 + 6, A); sq16(p, b0 + 7, B);
#pragma unroll
  for (int l = 0; l < 16; ++l) r67[l] = A[l] + B[l];
  float s[16];
#pragma unroll
  for (int l = 0; l < 16; ++l) s[l] = q0123[l] + (r45[l] + r67[l]);
  float t[8];
#pragma unroll
  for (int l = 0; l < 8; ++l) t[l] = s[l] + s[l + 8];
  float u[4];
#pragma unroll
  for (int l = 0; l < 4; ++l) u[l] = t[l] + t[l + 4];
  return (u[0] + u[2]) + (u[1] + u[3]);
}

__global__ __launch_bounds__(256) void vq_norms(const float* __restrict__ src,
                                                float* __restrict__ dst, int nrows) {
  const int row = blockIdx.x * blockDim.x + threadIdx.x;
  if (row >= nrows) return;
  const float4* p = reinterpret_cast<const float4*>(src + (size_t)row * DD);
  dst[row] = np_pw128_sq(p, 0) + np_pw128_sq(p, 8);
}

__global__ __launch_bounds__(256) void vq_init(unsigned* __restrict__ tmin, int n) {
  const int i = blockIdx.x * blockDim.x + threadIdx.x;
  if (i < n) tmin[i] = 0xFFFFFFFFu;
}

// ============ MFMA approx-distance pass ============
// 3-term bf16 split GEMM: mm^ = xh*ch + xh*cl + xl*ch (fp32 MFMA accum).
// P^ = (fl(xn+cn) - xn) - 2*mm^  (range ±0.03 -> fp32 resolution ~1e-9).
// tmin[row][tile64] = min P^ over the 64 codewords of the tile (monotone u32).
__device__ __forceinline__ unsigned short bf16_rne(float f) {
  unsigned u = __float_as_uint(f);
  return (unsigned short)((u + 0x7fffu + ((u >> 16) & 1u)) >> 16);
}
__device__ __forceinline__ int swz16(int row, int k) {  // u16-element offset in [128][32] tile
  return (row * 32 + k) ^ ((row & 7) << 3);             // 16B-granule XOR swizzle
}

__global__ __launch_bounds__(256) void vq_mfma(const float* __restrict__ x,
                                               const float* __restrict__ cb,
                                               const float* __restrict__ xn,
                                               const float* __restrict__ cn,
                                               unsigned* __restrict__ tmin) {
  __shared__ __align__(16) unsigned short sXH[128 * 32];
  __shared__ __align__(16) unsigned short sXL[128 * 32];
  __shared__ __align__(16) unsigned short sCH[128 * 32];
  __shared__ __align__(16) unsigned short sCL[128 * 32];

  const int tid = threadIdx.x;
  const int lane = tid & 63;
  const int wid = tid >> 6;
  const int wm = wid >> 1, wn = wid & 1;  // wave covers rows wm*64.., cols wn*64..
  const int row0 = blockIdx.x * 128;
  const int kc0 = blockIdx.y * 128;

  const int srow = tid >> 1;       // staging row 0..127
  const int sh = (tid & 1) * 16;   // staging d-offset half

  f32x4 acc[4][4];
#pragma unroll
  for (int m = 0; m < 4; ++m)
#pragma unroll
    for (int n = 0; n < 4; ++n) acc[m][n] = (f32x4)0.f;

  for (int dc = 0; dc < DD; dc += 32) {
    // load 16 fp32 of x-row and 16 of c-row to regs
    const float4* xg = reinterpret_cast<const float4*>(x + (size_t)(row0 + srow) * DD + dc + sh);
    const float4* cg = reinterpret_cast<const float4*>(cb + (size_t)(kc0 + srow) * DD + dc + sh);
    float fx[16], fc[16];
#pragma unroll
    for (int j = 0; j < 4; ++j) {
      const float4 v = xg[j];
      fx[4 * j] = v.x; fx[4 * j + 1] = v.y; fx[4 * j + 2] = v.z; fx[4 * j + 3] = v.w;
    }
#pragma unroll
    for (int j = 0; j < 4; ++j) {
      const float4 v = cg[j];
      fc[4 * j] = v.x; fc[4 * j + 1] = v.y; fc[4 * j + 2] = v.z; fc[4 * j + 3] = v.w;
    }
    // split to (hi,lo) bf16, packed 2-per-u32
    unsigned xhw[8], xlw[8], chw[8], clw[8];
#pragma unroll
    for (int j = 0; j < 8; ++j) {
      unsigned short h0 = bf16_rne(fx[2 * j]), h1 = bf16_rne(fx[2 * j + 1]);
      float hf0 = __uint_as_float((unsigned)h0 << 16), hf1 = __uint_as_float((unsigned)h1 << 16);
      unsigned short l0 = bf16_rne(fx[2 * j] - hf0), l1 = bf16_rne(fx[2 * j + 1] - hf1);
      xhw[j] = (unsigned)h0 | ((unsigned)h1 << 16);
      xlw[j] = (unsigned)l0 | ((unsigned)l1 << 16);
      h0 = bf16_rne(fc[2 * j]); h1 = bf16_rne(fc[2 * j + 1]);
      hf0 = __uint_as_float((unsigned)h0 << 16); hf1 = __uint_as_float((unsigned)h1 << 16);
      l0 = bf16_rne(fc[2 * j] - hf0); l1 = bf16_rne(fc[2 * j + 1] - hf1);
      chw[j] = (unsigned)h0 | ((unsigned)h1 << 16);
      clw[j] = (unsigned)l0 | ((unsigned)l1 << 16);
    }
    __syncthreads();  // prior iteration's fragment reads complete
#pragma unroll
    for (int half = 0; half < 2; ++half) {
      const int off = swz16(srow, sh + half * 8);
      *reinterpret_cast<uint4*>(&sXH[off]) = make_uint4(xhw[4 * half], xhw[4 * half + 1], xhw[4 * half + 2], xhw[4 * half + 3]);
      *reinterpret_cast<uint4*>(&sXL[off]) = make_uint4(xlw[4 * half], xlw[4 * half + 1], xlw[4 * half + 2], xlw[4 * half + 3]);
      *reinterpret_cast<uint4*>(&sCH[off]) = make_uint4(chw[4 * half], chw[4 * half + 1], chw[4 * half + 2], chw[4 * half + 3]);
      *reinterpret_cast<uint4*>(&sCL[off]) = make_uint4(clw[4 * half], clw[4 * half + 1], clw[4 * half + 2], clw[4 * half + 3]);
    }
    __syncthreads();

    // fragment loads + MFMA. A/B frag: elem i of lane = M[base + (lane&15)][8*(lane>>4)+i]
    const int kg = (lane >> 4) * 8;
    short8 fbh[4], fbl[4];
#pragma unroll
    for (int n = 0; n < 4; ++n) {
      const int off = swz16(wn * 64 + n * 16 + (lane & 15), kg);
      fbh[n] = *reinterpret_cast<const short8*>(&sCH[off]);
      fbl[n] = *reinterpret_cast<const short8*>(&sCL[off]);
    }
#pragma unroll
    for (int m = 0; m < 4; ++m) {
      const int off = swz16(wm * 64 + m * 16 + (lane & 15), kg);
      const short8 fah = *reinterpret_cast<const short8*>(&sXH[off]);
      const short8 fal = *reinterpret_cast<const short8*>(&sXL[off]);
#pragma unroll
      for (int n = 0; n < 4; ++n) {
        acc[m][n] = __builtin_amdgcn_mfma_f32_16x16x32_bf16(fah, fbh[n], acc[m][n], 0, 0, 0);
        acc[m][n] = __builtin_amdgcn_mfma_f32_16x16x32_bf16(fah, fbl[n], acc[m][n], 0, 0, 0);
        acc[m][n] = __builtin_amdgcn_mfma_f32_16x16x32_bf16(fal, fbh[n], acc[m][n], 0, 0, 0);
      }
    }
  }

  // epilogue: P^ per element; D layout: col = lane&15, row = 4*(lane>>4)+j (m89-verified)
  const int lr = lane >> 4, lc = lane & 15;
  const int tile = blockIdx.y * 2 + wn;
#pragma unroll
  for (int m = 0; m < 4; ++m) {
    float xnv[4];
#pragma unroll
    for (int j = 0; j < 4; ++j) xnv[j] = xn[row0 + wm * 64 + m * 16 + lr * 4 + j];
    float pm[4] = {INFINITY, INFINITY, INFINITY, INFINITY};
#pragma unroll
    for (int n = 0; n < 4; ++n) {
      const float cnv = cn[kc0 + wn * 64 + n * 16 + lc];
#pragma unroll
      for (int j = 0; j < 4; ++j) {
        const float A = xnv[j] + cnv;                       // fl(xn+cn)
        const float p = fmaf(-2.f, acc[m][n][j], A - xnv[j]);  // (A-xn) exact (Sterbenz)
        pm[j] = fminf(pm[j], p);
      }
    }
#pragma unroll
    for (int off = 1; off < 16; off <<= 1) {
#pragma unroll
      for (int j = 0; j < 4; ++j) pm[j] = fminf(pm[j], __shfl_xor(pm[j], off));
    }
    if (lc == 0) {
#pragma unroll
      for (int j = 0; j < 4; ++j) {
        const int row = row0 + wm * 64 + m * 16 + lr * 4 + j;
        atomicMin(&tmin[(size_t)row * 64 + tile], mono(pm[j]));
      }
    }
  }
}

// ============ exact rescore of qualifying tiles ============
// For each row: gmin = min tmin; tiles with tmin < gmin + W get all 64 k's
// re-scored with the exact ascending-d fp32 FMA chain + exact numpy epilogue.
// Lex-min on (mono(dist) || k) == numpy first-index argmin.
__global__ __launch_bounds__(256) void vq_rescore(const float* __restrict__ x,
                                                  const float* __restrict__ cb,
                                                  const float* __restrict__ xn,
                                                  const float* __restrict__ cn,
                                                  const unsigned* __restrict__ tmin,
                                                  int* __restrict__ inds) {
  const int lane = threadIdx.x & 63;
  const int row = blockIdx.x * 4 + (threadIdx.x >> 6);
  const unsigned tv = tmin[(size_t)row * 64 + lane];
  unsigned mv = tv;
#pragma unroll
  for (int off = 32; off; off >>= 1) mv = min(mv, (unsigned)__shfl_xor((int)mv, off));
  const float xnr = xn[row];
  // W >= ulp(dist) + 2*approx_err + safety:  ulp <= xn*2.4e-7
  const float thresh = unmono(mv) + (xnr * 3e-7f + 4e-6f);
  const unsigned tq = mono(thresh);
  unsigned long long qmask = __ballot(tv <= tq);

  const float* xp = x + (size_t)row * DD;
  unsigned long long best = ~0ull;
  while (qmask) {
    const int s = __ffsll(qmask) - 1;
    qmask &= qmask - 1;
    const int k = s * 64 + lane;
    const float* cp = cb + (size_t)k * DD;
    float dot = 0.f;
#pragma unroll 8
    for (int d = 0; d < DD; ++d) dot = fmaf(xp[d], cp[d], dot);
    const float A = xnr + cn[k];
    const float dist = fmaf(-2.f, dot, A);  // == fl(A - fl(2*dot)) (2*dot exact)
    const unsigned long long cand = ((unsigned long long)mono(dist) << 32) | (unsigned)k;
    best = best < cand ? best : cand;
  }
#pragma unroll
  for (int off = 32; off; off >>= 1) {
    const unsigned long long o = __shfl_xor(best, off);
    best = best < o ? best : o;
  }
  if (lane == 0) inds[row] = (int)(best & 0xffffffffu);
}

// ============ gather + STE output ============
__global__ __launch_bounds__(256) void vq_out(const float* __restrict__ x,
                                              const float* __restrict__ cb,
                                              const int* __restrict__ inds,
                                              float* __restrict__ out) {
  const int w = (blockIdx.x * blockDim.x + threadIdx.x) >> 6;
  const int lane = threadIdx.x & 63;
  if (w >= NN) return;
  const int k = inds[w];
  const float4 xv = *reinterpret_cast<const float4*>(x + (size_t)w * DD + lane * 4);
  const float4 cv = *reinterpret_cast<const float4*>(cb + (size_t)k * DD + lane * 4);
  float4 o;
  o.x = xv.x + (cv.x - xv.x);
  o.y = xv.y + (cv.y - xv.y);
  o.z = xv.z + (cv.z - xv.z);
  o.w = xv.w + (cv.w - xv.w);
  *reinterpret_cast<float4*>(out + (size_t)w * DD + lane * 4) = o;
}

extern "C" void kernel_launch(void* const* d_in, const int* in_sizes, int n_in,
                              void* d_out, int out_size, void* d_ws, size_t ws_size,
                              hipStream_t stream) {
  const float* x = (const float*)d_in[0];
  const float* cb = (const float*)d_in[1];
  float* out = (float*)d_out;

  // ws: xn 128KB @0 | cn 16KB @128K | tmin 8MB @144K | inds 128KB @ 144K+8M
  float* xn = (float*)d_ws;
  float* cn = (float*)((char*)d_ws + 131072);
  unsigned* tmin = (unsigned*)((char*)d_ws + 147456);
  int* inds = (int*)((char*)d_ws + 147456 + (size_t)NN * 64 * 4);

  vq_init<<<(NN * 64) / 256, 256, 0, stream>>>(tmin, NN * 64);
  vq_norms<<<NN / 256, 256, 0, stream>>>(x, xn, NN);
  vq_norms<<<KK / 256, 256, 0, stream>>>(cb, cn, KK);
  dim3 mgrid(NN / 128, KK / 128);
  vq_mfma<<<mgrid, 256, 0, stream>>>(x, cb, xn, cn, tmin);
  vq_rescore<<<NN / 4, 256, 0, stream>>>(x, cb, xn, cn, tmin, inds);
  vq_out<<<NN / 4, 256, 0, stream>>>(x, cb, inds, out);
}